// Round 15
// baseline (1970.630 us; speedup 1.0000x reference)
//
#include <hip/hip_runtime.h>

typedef _Float16 f16;
typedef _Float16 f16x8 __attribute__((ext_vector_type(8)));
typedef _Float16 f16x4 __attribute__((ext_vector_type(4)));
typedef _Float16 f16x2 __attribute__((ext_vector_type(2)));
typedef float f32x4 __attribute__((ext_vector_type(4)));

#define B_ 128
#define T_ 512
#define H_ 192
#define G3 576

// gate prescale constants (folded into weights/biases):
// r,z pre-acts scaled by -log2e  -> sigmoid(u) = rcp(1 + exp2(u~))
// n pre-acts scaled by +2*log2e  -> tanh(v) = 1 - 2*rcp(1 + exp2(v~))
#define SC_RZ (-1.44269504088896f)
#define SC_N  (2.88539008177793f)

// ---- workspace layout (bytes). Total 255,049,728 < 256 MiB. ----
// [0, 201326592)           gxb : gx pre-acts, f16 [d*128+row][t][c*4+s] (768 slots/t,
//                                slot s=3 is pad; one aligned f16x4 per (row,t,c))
// [201326592, 251658240)   hbuf: layer h output, f16 [t][b][384]
//                                (in0 f16 [t][b][128] aliases its first 16.8MB)
// [251658240, 253722624)   wihf: f16 w_ih prescaled (L0 147456, L1 442368, L2 442368)
// [253722624, 255049728)   whhf: f16 w_hh prescaled (3 x 221184)
#define OFF_H   201326592u
#define OFF_WIH 251658240u
#define OFF_WHH 253722624u

__device__ __forceinline__ void gload_lds16(const void* g, void* l) {
  __builtin_amdgcn_global_load_lds(
      (const __attribute__((address_space(1))) unsigned int*)g,
      (__attribute__((address_space(3))) unsigned int*)l, 16, 0, 0);
}

#if __has_builtin(__builtin_amdgcn_fdot2)
__device__ __forceinline__ float fdot2_(f16x2 a, f16x2 b, float c) {
  return __builtin_amdgcn_fdot2(a, b, c, false);
}
#else
__device__ __forceinline__ float fdot2_(f16x2 a, f16x2 b, float c) {
  return fmaf((float)a[1], (float)b[1], fmaf((float)a[0], (float)b[0], c));
}
#endif

// ---------------- weight f32 -> f16 conversion with gate prescale ----------------
__global__ void wconv_kernel(const float* __restrict__ w0, const float* __restrict__ h0,
                             const float* __restrict__ w1, const float* __restrict__ h1,
                             const float* __restrict__ w2, const float* __restrict__ h2,
                             f16* __restrict__ wih, f16* __restrict__ whh) {
  const int stride = gridDim.x * blockDim.x;
  for (int i = blockIdx.x * blockDim.x + threadIdx.x; i < 1695744; i += stride) {
    if (i < 1032192) {
      int j, din;
      const float* src;
      if (i < 147456) { j = i; din = 128; src = w0; }
      else if (i < 589824) { j = i - 147456; din = 384; src = w1; }
      else { j = i - 589824; din = 384; src = w2; }
      const int row = j / din;            // 0..1151 = [d][576]
      const int sg = (row % 576) / 192;   // gate type r/z/n
      wih[i] = (f16)(src[j] * (sg == 2 ? SC_N : SC_RZ));
    } else {
      int j = i - 1032192, jl;
      const float* src;
      if (j < 221184) { src = h0; jl = j; }
      else if (j < 442368) { src = h1; jl = j - 221184; }
      else { src = h2; jl = j - 442368; }
      const int row = jl / 192;           // 0..1151
      const int sg = (row % 576) / 192;
      whh[j] = (f16)(src[jl] * (sg == 2 ? SC_N : SC_RZ));
    }
  }
}

// ---------------- embedding gather -> f16, out layout [t][b][128] ----------------
__global__ void embed_kernel(const int* __restrict__ x, const float* __restrict__ emb,
                             f16* __restrict__ o) {
  const int row = (blockIdx.x << 2) + (threadIdx.x >> 6);  // b*512+t
  const int lane = threadIdx.x & 63;
  const int b = row >> 9, t = row & 511;
  const int idx = x[row];
  const float2 v = *(const float2*)(emb + ((size_t)idx << 7) + (lane << 1));
  union { f16 h[2]; unsigned u; } p;
  p.h[0] = (f16)v.x;
  p.h[1] = (f16)v.y;
  *(unsigned*)(o + ((size_t)((t << 7) + b) << 7) + (lane << 1)) = p.u;
}

// ---------------- gx GEMM: gx = X @ w_ih^T + b_ih (f16 MFMA, prescaled) ----------------
template <int DIN>
__global__ __launch_bounds__(256) void gx_gemm(const f16* __restrict__ A,
                                               const f16* __restrict__ W,
                                               const float* __restrict__ bih,
                                               f16* __restrict__ gxo) {
  const int t = blockIdx.x;
  const int nt0 = blockIdx.y << 7;
  const int tid = threadIdx.x;
  const int lane = tid & 63;
  const int w = tid >> 6;
  const int l16 = lane & 15;
  const int lq = lane >> 4;
  const int wm = (w >> 1) << 6;
  const int wn = (w & 1) << 6;

  __shared__ __align__(16) f16 Al[128 * 128];
  __shared__ __align__(16) f16 Bl[128 * 128];

  f32x4 acc[4][4] = {};

  const int srow = tid >> 4;
  const int sc = tid & 15;

  for (int kk = 0; kk < DIN; kk += 128) {
    __syncthreads();
#pragma unroll
    for (int it = 0; it < 8; ++it) {
      const int r = (it << 4) + srow;
      const int cl = sc ^ (r & 7);
      gload_lds16(A + (size_t)(t * B_ + r) * DIN + kk + cl * 8, Al + (it << 11) + tid * 8);
      const int n = nt0 + r;
      gload_lds16(W + (size_t)n * DIN + kk + cl * 8, Bl + (it << 11) + tid * 8);
    }
    __syncthreads();
#pragma unroll
    for (int kt = 0; kt < 4; ++kt) {
      f16x8 af[4], bf[4];
#pragma unroll
      for (int mt = 0; mt < 4; ++mt) {
        const int r = wm + (mt << 4) + l16;
        const int c = ((kt << 2) + lq) ^ (r & 7);
        af[mt] = *(const f16x8*)(Al + (r << 7) + (c << 3));
      }
#pragma unroll
      for (int nt = 0; nt < 4; ++nt) {
        const int r = wn + (nt << 4) + l16;
        const int c = ((kt << 2) + lq) ^ (r & 7);
        bf[nt] = *(const f16x8*)(Bl + (r << 7) + (c << 3));
      }
#pragma unroll
      for (int mt = 0; mt < 4; ++mt)
#pragma unroll
        for (int nt = 0; nt < 4; ++nt)
          acc[mt][nt] = __builtin_amdgcn_mfma_f32_16x16x32_f16(af[mt], bf[nt], acc[mt][nt], 0, 0, 0);
    }
  }
  // epilogue: + prescaled b_ih; scatter to scan layout [d*128+b][t][c*4+s].
  // C frag: row(batch) = lq*4+i, col(gate) = l16.
#pragma unroll
  for (int nt = 0; nt < 4; ++nt) {
    const int ncol = nt0 + wn + (nt << 4);
    const int ntile = ncol >> 4;                 // 0..71
    const int dd = (ntile >= 36) ? 1 : 0;
    const int g16 = ntile - 36 * dd;
    const int s = g16 / 12;                      // gate type r/z/n
    const int cc = (g16 % 12) * 16 + l16;        // h-col 0..191
    const float bias = bih[ncol + l16] * ((s == 2) ? SC_N : SC_RZ);
#pragma unroll
    for (int mt = 0; mt < 4; ++mt) {
#pragma unroll
      for (int i = 0; i < 4; ++i) {
        const int b = wm + (mt << 4) + (lq << 2) + i;
        const size_t off = ((size_t)(dd * 128 + b) * 512 + t) * 768 + cc * 4 + s;
        gxo[off] = (f16)(acc[mt][nt][i] + bias);
      }
    }
  }
}

// ---------------- recurrent scan: dot2-GEMV, 1 row/block, 256 blocks ----------------
// 256 blocks x 768 threads. Block = one (row, dir) recurrence. Lane L owns
// quarter-dots 3L..3L+2 (QI = hrow*4+q); its 144 weights contiguous at
// whd+144L, PINNED in VGPRs via empty-asm "+v" (round-14 bug: compiler
// rematerialized the weight loads into the loop -> VGPR=64 + per-step global
// traffic drained at every barrier). gx loaded in 8-step batches (one drain
// per group); out-stores batched 8 steps in registers, flushed at the top of
// the next group so their drain hides under GEMV.
__global__ __launch_bounds__(768, 1) void gru_scan(const f16* __restrict__ gx,
                                                   const f16* __restrict__ whh,
                                                   const float* __restrict__ bhh,
                                                   f16* __restrict__ out,
                                                   int last) {
  const int bx = blockIdx.x;   // 0..255
  const int d = bx >> 7;
  const int row = bx & 127;
  const int tid = threadIdx.x;

  __shared__ __align__(16) f16 hB[2][192];
  __shared__ __align__(16) float accQ[2304];
  if (tid < 384) ((f16*)hB)[tid] = (f16)0.f;

  // GEMV weights: 144 contiguous f16 at whd + 144*tid, pinned in VGPRs
  const f16* wp = whh + (size_t)d * (G3 * H_) + (size_t)tid * 144;
  f16x2 wreg[72];
#pragma unroll
  for (int j = 0; j < 72; ++j) wreg[j] = *(const f16x2*)(wp + 2 * j);
#pragma unroll
  for (int j = 0; j < 72; ++j) asm volatile("" : "+v"(wreg[j]));
  int hoff[3];
#pragma unroll
  for (int j = 0; j < 3; ++j) hoff[j] = ((3 * tid + j) & 3) * 96;  // byte offset of quarter

  const int nsteps = (last && d == 1) ? 1 : T_;
  const bool fwd = (d == 0);
  const int t0 = fwd ? 0 : (T_ - 1);
  const long gstep = fwd ? 768 : -768;                 // f16 elems per t-step
  const long ostep = fwd ? (long)(B_ * 384) : -(long)(B_ * 384);

  // gate-lane (tid<192) state
  float bias_r = 0.f, bias_z = 0.f, bias_n = 0.f, hr = 0.f;
  const f16* gptr = gx;
  f16* outp = out;
  if (tid < 192) {
    bias_r = bhh[d * G3 + tid] * SC_RZ;
    bias_z = bhh[d * G3 + 192 + tid] * SC_RZ;
    bias_n = bhh[d * G3 + 384 + tid] * SC_N;
    gptr = gx + ((size_t)(d * 128 + row) * 512 + t0) * 768 + tid * 4;
    outp = out + ((size_t)t0 * B_ + row) * 384 + d * H_ + tid;
  }
  f16x4 pr[8];
#pragma unroll
  for (int j = 0; j < 8; ++j) pr[j] = (f16x4){};
  f16 h0_ = (f16)0.f, h1_ = (f16)0.f, h2_ = (f16)0.f, h3_ = (f16)0.f;
  f16 h4_ = (f16)0.f, h5_ = (f16)0.f, h6_ = (f16)0.f, h7_ = (f16)0.f;
  __syncthreads();

  auto flush8 = [&]() {
    *(outp - 8 * ostep) = h0_;
    *(outp - 7 * ostep) = h1_;
    *(outp - 6 * ostep) = h2_;
    *(outp - 5 * ostep) = h3_;
    *(outp - 4 * ostep) = h4_;
    *(outp - 3 * ostep) = h5_;
    *(outp - 2 * ostep) = h6_;
    *(outp - 1 * ostep) = h7_;
  };

  // one step; ph = k&7 as a literal for register-resident store history
  auto body = [&](int k, const f16x4 gcur, const int ph) {
    // flush previous group's out-stores here: the next barrier's vmcnt drain
    // then overlaps this step's GEMV phase
    if (ph == 0 && !last && k > 0 && tid < 192) flush8();
    // ---- GEMV (all 768 lanes) ----
    const char* hp = (const char*)hB[k & 1];
    float a0 = 0.f, a1 = 0.f, a2 = 0.f;
#pragma unroll
    for (int jc = 0; jc < 6; ++jc) {
      const f16x8 h8 = *(const f16x8*)(hp + hoff[0] + jc * 16);
      const f16x2* h2 = (const f16x2*)&h8;
#pragma unroll
      for (int e = 0; e < 4; ++e) a0 = fdot2_(h2[e], wreg[jc * 4 + e], a0);
    }
#pragma unroll
    for (int jc = 0; jc < 6; ++jc) {
      const f16x8 h8 = *(const f16x8*)(hp + hoff[1] + jc * 16);
      const f16x2* h2 = (const f16x2*)&h8;
#pragma unroll
      for (int e = 0; e < 4; ++e) a1 = fdot2_(h2[e], wreg[24 + jc * 4 + e], a1);
    }
#pragma unroll
    for (int jc = 0; jc < 6; ++jc) {
      const f16x8 h8 = *(const f16x8*)(hp + hoff[2] + jc * 16);
      const f16x2* h2 = (const f16x2*)&h8;
#pragma unroll
      for (int e = 0; e < 4; ++e) a2 = fdot2_(h2[e], wreg[48 + jc * 4 + e], a2);
    }
    accQ[3 * tid] = a0;
    accQ[3 * tid + 1] = a1;
    accQ[3 * tid + 2] = a2;
    __syncthreads();
    // ---- gates (lanes 0..191) ----
    if (tid < 192) {
      const f32x4 q0 = *(const f32x4*)&accQ[4 * tid];
      const f32x4 q1 = *(const f32x4*)&accQ[768 + 4 * tid];
      const f32x4 q2 = *(const f32x4*)&accQ[1536 + 4 * tid];
      const float ar = bias_r + ((q0[0] + q0[1]) + (q0[2] + q0[3]));
      const float az = bias_z + ((q1[0] + q1[1]) + (q1[2] + q1[3]));
      const float an = bias_n + ((q2[0] + q2[1]) + (q2[2] + q2[3]));
      const float ur = (float)gcur[0] + ar;
      const float uz = (float)gcur[1] + az;
      const float dr = 1.f + __builtin_amdgcn_exp2f(ur);
      const float dz = 1.f + __builtin_amdgcn_exp2f(uz);
      const float Rp = __builtin_amdgcn_rcpf(dr * dz);
      const float rv = dz * Rp, zv = dr * Rp;
      const float vn = fmaf(rv, an, (float)gcur[2]);
      const float nv = fmaf(-2.f, __builtin_amdgcn_rcpf(1.f + __builtin_amdgcn_exp2f(vn)), 1.f);
      const float hv = nv + zv * (hr - nv);
      hr = hv;
      hB[(k & 1) ^ 1][tid] = (f16)hv;
      if (!last) {
        if (ph == 0) h0_ = (f16)hv;
        else if (ph == 1) h1_ = (f16)hv;
        else if (ph == 2) h2_ = (f16)hv;
        else if (ph == 3) h3_ = (f16)hv;
        else if (ph == 4) h4_ = (f16)hv;
        else if (ph == 5) h5_ = (f16)hv;
        else if (ph == 6) h6_ = (f16)hv;
        else h7_ = (f16)hv;
      } else {
        const int t = fwd ? k : (T_ - 1 - k);
        if (t == T_ - 1) *outp = (f16)hv;
      }
      outp += ostep;
    }
    __syncthreads();
  };

  if (nsteps == 1) {
    if (tid < 192) pr[0] = *(const f16x4*)gptr;
    body(0, pr[0], 0);
  } else {
    for (int k = 0; k < T_; k += 8) {
      // batched gx load for this 8-step group (one vmcnt-drain per group)
      if (tid < 192) {
#pragma unroll
        for (int j = 0; j < 8; ++j) pr[j] = *(const f16x4*)(gptr + j * gstep);
        gptr += 8 * gstep;
      }
      body(k + 0, pr[0], 0);
      body(k + 1, pr[1], 1);
      body(k + 2, pr[2], 2);
      body(k + 3, pr[3], 3);
      body(k + 4, pr[4], 4);
      body(k + 5, pr[5], 5);
      body(k + 6, pr[6], 6);
      body(k + 7, pr[7], 7);
    }
    if (!last && tid < 192) flush8();
  }
}

// ---------------- FC head ----------------
__global__ void fc_kernel(const f16* __restrict__ h2, const float* __restrict__ w1,
                          const float* __restrict__ b1, const float* __restrict__ w2,
                          const float* __restrict__ b2, float* __restrict__ y) {
  const int b = blockIdx.x;
  const int i = threadIdx.x;
  __shared__ float hs[384];
  __shared__ float us[128];
  const f16* hp = h2 + ((size_t)(T_ - 1) * B_ + b) * 384;
  for (int k = i; k < 384; k += 128) hs[k] = (float)hp[k];
  __syncthreads();
  float a = b1[i];
  for (int k = 0; k < 384; ++k) a = fmaf(w1[i * 384 + k], hs[k], a);
  us[i] = fmaxf(a, 0.f) * w2[i];
  __syncthreads();
  if (i == 0) {
    float s = b2[0];
    for (int k = 0; k < 128; ++k) s += us[k];
    y[b] = s;
  }
}

extern "C" void kernel_launch(void* const* d_in, const int* in_sizes, int n_in,
                              void* d_out, int out_size, void* d_ws, size_t ws_size,
                              hipStream_t stream) {
  const int* x = (const int*)d_in[0];
  const float* emb = (const float*)d_in[1];
  const float* wih[3] = {(const float*)d_in[2], (const float*)d_in[6], (const float*)d_in[10]};
  const float* whh[3] = {(const float*)d_in[3], (const float*)d_in[7], (const float*)d_in[11]};
  const float* bih[3] = {(const float*)d_in[4], (const float*)d_in[8], (const float*)d_in[12]};
  const float* bhh[3] = {(const float*)d_in[5], (const float*)d_in[9], (const float*)d_in[13]};
  const float* fc1w = (const float*)d_in[14];
  const float* fc1b = (const float*)d_in[15];
  const float* fc2w = (const float*)d_in[16];
  const float* fc2b = (const float*)d_in[17];
  float* y = (float*)d_out;

  char* ws = (char*)d_ws;
  f16* gxb = (f16*)(ws);
  f16* hbuf = (f16*)(ws + OFF_H);
  f16* in0 = hbuf;
  f16* wihf = (f16*)(ws + OFF_WIH);
  f16* whhf = (f16*)(ws + OFF_WHH);

  wconv_kernel<<<1024, 256, 0, stream>>>(wih[0], whh[0], wih[1], whh[1], wih[2], whh[2], wihf, whhf);
  embed_kernel<<<16384, 256, 0, stream>>>(x, emb, in0);

  gx_gemm<128><<<dim3(512, 9), 256, 0, stream>>>(in0, wihf, bih[0], gxb);
  gru_scan<<<256, 768, 0, stream>>>(gxb, whhf, bhh[0], hbuf, 0);
  gx_gemm<384><<<dim3(512, 9), 256, 0, stream>>>(hbuf, wihf + 147456, bih[1], gxb);
  gru_scan<<<256, 768, 0, stream>>>(gxb, whhf + 221184, bhh[1], hbuf, 0);
  gx_gemm<384><<<dim3(512, 9), 256, 0, stream>>>(hbuf, wihf + 147456 + 442368, bih[2], gxb);
  gru_scan<<<256, 768, 0, stream>>>(gxb, whhf + 2 * 221184, bhh[2], hbuf, 1);

  fc_kernel<<<128, 128, 0, stream>>>(hbuf, fc1w, fc1b, fc2w, fc2b, y);
}

// Round 16
// 1875.398 us; speedup vs baseline: 1.0508x; 1.0508x over previous
//
#include <hip/hip_runtime.h>

typedef _Float16 f16;
typedef _Float16 f16x8 __attribute__((ext_vector_type(8)));
typedef _Float16 f16x4 __attribute__((ext_vector_type(4)));
typedef _Float16 f16x2 __attribute__((ext_vector_type(2)));
typedef float f32x4 __attribute__((ext_vector_type(4)));

#define B_ 128
#define T_ 512
#define H_ 192
#define G3 576

// gate prescale constants (folded into weights/biases):
// r,z pre-acts scaled by -log2e  -> sigmoid(u) = rcp(1 + exp2(u~))
// n pre-acts scaled by +2*log2e  -> tanh(v) = 1 - 2*rcp(1 + exp2(v~))
#define SC_RZ (-1.44269504088896f)
#define SC_N  (2.88539008177793f)

// ---- workspace layout (bytes). Total 255,049,728 < 256 MiB. ----
// [0, 201326592)           gxb : gx pre-acts, f16 [d*128+row][t][c*4+s] (768 slots/t,
//                                slot s=3 is pad; one aligned f16x4 per (row,t,c))
// [201326592, 251658240)   hbuf: layer h output, f16 [t][b][384]
//                                (in0 f16 [t][b][128] aliases its first 16.8MB)
// [251658240, 253722624)   wihf: f16 w_ih prescaled (L0 147456, L1 442368, L2 442368)
// [253722624, 255049728)   whhf: f16 w_hh prescaled (3 x 221184)
#define OFF_H   201326592u
#define OFF_WIH 251658240u
#define OFF_WHH 253722624u

__device__ __forceinline__ void gload_lds16(const void* g, void* l) {
  __builtin_amdgcn_global_load_lds(
      (const __attribute__((address_space(1))) unsigned int*)g,
      (__attribute__((address_space(3))) unsigned int*)l, 16, 0, 0);
}

// ---------------- weight f32 -> f16 conversion with gate prescale ----------------
__global__ void wconv_kernel(const float* __restrict__ w0, const float* __restrict__ h0,
                             const float* __restrict__ w1, const float* __restrict__ h1,
                             const float* __restrict__ w2, const float* __restrict__ h2,
                             f16* __restrict__ wih, f16* __restrict__ whh) {
  const int stride = gridDim.x * blockDim.x;
  for (int i = blockIdx.x * blockDim.x + threadIdx.x; i < 1695744; i += stride) {
    if (i < 1032192) {
      int j, din;
      const float* src;
      if (i < 147456) { j = i; din = 128; src = w0; }
      else if (i < 589824) { j = i - 147456; din = 384; src = w1; }
      else { j = i - 589824; din = 384; src = w2; }
      const int row = j / din;            // 0..1151 = [d][576]
      const int sg = (row % 576) / 192;   // gate type r/z/n
      wih[i] = (f16)(src[j] * (sg == 2 ? SC_N : SC_RZ));
    } else {
      int j = i - 1032192, jl;
      const float* src;
      if (j < 221184) { src = h0; jl = j; }
      else if (j < 442368) { src = h1; jl = j - 221184; }
      else { src = h2; jl = j - 442368; }
      const int row = jl / 192;           // 0..1151
      const int sg = (row % 576) / 192;
      whh[j] = (f16)(src[jl] * (sg == 2 ? SC_N : SC_RZ));
    }
  }
}

// ---------------- embedding gather -> f16, out layout [t][b][128] ----------------
__global__ void embed_kernel(const int* __restrict__ x, const float* __restrict__ emb,
                             f16* __restrict__ o) {
  const int row = (blockIdx.x << 2) + (threadIdx.x >> 6);  // b*512+t
  const int lane = threadIdx.x & 63;
  const int b = row >> 9, t = row & 511;
  const int idx = x[row];
  const float2 v = *(const float2*)(emb + ((size_t)idx << 7) + (lane << 1));
  union { f16 h[2]; unsigned u; } p;
  p.h[0] = (f16)v.x;
  p.h[1] = (f16)v.y;
  *(unsigned*)(o + ((size_t)((t << 7) + b) << 7) + (lane << 1)) = p.u;
}

// ---------------- gx GEMM: gx = X @ w_ih^T + b_ih (f16 MFMA, prescaled) ----------------
template <int DIN>
__global__ __launch_bounds__(256) void gx_gemm(const f16* __restrict__ A,
                                               const f16* __restrict__ W,
                                               const float* __restrict__ bih,
                                               f16* __restrict__ gxo) {
  const int t = blockIdx.x;
  const int nt0 = blockIdx.y << 7;
  const int tid = threadIdx.x;
  const int lane = tid & 63;
  const int w = tid >> 6;
  const int l16 = lane & 15;
  const int lq = lane >> 4;
  const int wm = (w >> 1) << 6;
  const int wn = (w & 1) << 6;

  __shared__ __align__(16) f16 Al[128 * 128];
  __shared__ __align__(16) f16 Bl[128 * 128];

  f32x4 acc[4][4] = {};

  const int srow = tid >> 4;
  const int sc = tid & 15;

  for (int kk = 0; kk < DIN; kk += 128) {
    __syncthreads();
#pragma unroll
    for (int it = 0; it < 8; ++it) {
      const int r = (it << 4) + srow;
      const int cl = sc ^ (r & 7);
      gload_lds16(A + (size_t)(t * B_ + r) * DIN + kk + cl * 8, Al + (it << 11) + tid * 8);
      const int n = nt0 + r;
      gload_lds16(W + (size_t)n * DIN + kk + cl * 8, Bl + (it << 11) + tid * 8);
    }
    __syncthreads();
#pragma unroll
    for (int kt = 0; kt < 4; ++kt) {
      f16x8 af[4], bf[4];
#pragma unroll
      for (int mt = 0; mt < 4; ++mt) {
        const int r = wm + (mt << 4) + l16;
        const int c = ((kt << 2) + lq) ^ (r & 7);
        af[mt] = *(const f16x8*)(Al + (r << 7) + (c << 3));
      }
#pragma unroll
      for (int nt = 0; nt < 4; ++nt) {
        const int r = wn + (nt << 4) + l16;
        const int c = ((kt << 2) + lq) ^ (r & 7);
        bf[nt] = *(const f16x8*)(Bl + (r << 7) + (c << 3));
      }
#pragma unroll
      for (int mt = 0; mt < 4; ++mt)
#pragma unroll
        for (int nt = 0; nt < 4; ++nt)
          acc[mt][nt] = __builtin_amdgcn_mfma_f32_16x16x32_f16(af[mt], bf[nt], acc[mt][nt], 0, 0, 0);
    }
  }
  // epilogue: + prescaled b_ih; scatter to scan layout [d*128+b][t][c*4+s].
  // C frag: row(batch) = lq*4+i, col(gate) = l16.
#pragma unroll
  for (int nt = 0; nt < 4; ++nt) {
    const int ncol = nt0 + wn + (nt << 4);
    const int ntile = ncol >> 4;                 // 0..71
    const int dd = (ntile >= 36) ? 1 : 0;
    const int g16 = ntile - 36 * dd;
    const int s = g16 / 12;                      // gate type r/z/n
    const int cc = (g16 % 12) * 16 + l16;        // h-col 0..191
    const float bias = bih[ncol + l16] * ((s == 2) ? SC_N : SC_RZ);
#pragma unroll
    for (int mt = 0; mt < 4; ++mt) {
#pragma unroll
      for (int i = 0; i < 4; ++i) {
        const int b = wm + (mt << 4) + (lq << 2) + i;
        const size_t off = ((size_t)(dd * 128 + b) * 512 + t) * 768 + cc * 4 + s;
        gxo[off] = (f16)(acc[mt][nt][i] + bias);
      }
    }
  }
}

// ---------------- recurrent scan: 1 (row,dir)/block, 256 blocks x 256 threads ----------------
// One wave per SIMD, whole chip active. Wave w owns gate cols [48w,48w+48):
// wf[3][3][6] = 216 VGPR resident (4 waves/CU -> 512-VGPR cap, no spill pressure).
// A-frag = h row dup x16 (broadcast LDS read); acc[s][q] duplicated over lq, so
// EVERY lane computes its 3 gate cols fully locally (lq==0 lanes store).
// Gate VALU no longer stacks per SIMD (was 3 waves x 330cy in r11).
// gx: 3x f16x4/lane from [d*128+row][t][c*4+s] layout, 4-step batched loads;
// out: 4-step register history, flushed at group top. 1 barrier/step.
__global__ __launch_bounds__(256, 1) void gru_scan(const f16* __restrict__ gx,
                                                   const f16* __restrict__ whh,
                                                   const float* __restrict__ bhh,
                                                   f16* __restrict__ out,
                                                   int last) {
  const int bx = blockIdx.x;   // 0..255
  const int d = bx >> 7;
  const int row = bx & 127;
  const int tid = threadIdx.x;
  const int lane = tid & 63;
  const int w = tid >> 6;      // 0..3
  const int l16 = lane & 15;
  const int lq = lane >> 4;

  __shared__ __align__(16) f16 hT[2][192];
  if (tid < 192) { hT[0][tid] = (f16)0.f; hT[1][tid] = (f16)0.f; }

  // resident weights: wave w's 48 gate cols x 3 gate types
  const f16* whd = whh + (size_t)d * (G3 * H_);
  f16x8 wf[3][3][6];
#pragma unroll
  for (int s = 0; s < 3; ++s)
#pragma unroll
    for (int q = 0; q < 3; ++q) {
      const int nrow = s * 192 + w * 48 + q * 16 + l16;
#pragma unroll
      for (int kt = 0; kt < 6; ++kt)
        wf[s][q][kt] = *(const f16x8*)(whd + (size_t)nrow * H_ + kt * 32 + lq * 8);
    }
  f32x4 bh4[3][3];
#pragma unroll
  for (int s = 0; s < 3; ++s)
#pragma unroll
    for (int q = 0; q < 3; ++q) {
      const float bv = bhh[d * G3 + s * 192 + w * 48 + q * 16 + l16] * ((s == 2) ? SC_N : SC_RZ);
      bh4[s][q] = (f32x4){bv, bv, bv, bv};
    }

  float hr0 = 0.f, hr1 = 0.f, hr2 = 0.f;   // prev h for this lane's 3 cols

  const int nsteps = (last && d == 1) ? 1 : T_;
  const bool fwd = (d == 0);
  const int t0 = fwd ? 0 : (T_ - 1);
  const long gstep = fwd ? 768 : -768;
  const long ostep = fwd ? (long)(B_ * 384) : -(long)(B_ * 384);

  const f16* gptr = gx + ((size_t)(d * 128 + row) * 512 + t0) * 768 + (w * 48 + l16) * 4;
  f16* outp = out + ((size_t)t0 * B_ + row) * 384 + d * H_ + w * 48 + l16;
  const bool writer = (lq == 0);

  f16x4 pr0[4], pr1[4], pr2[4];
  f16x4 hist0 = {}, hist1 = {}, hist2 = {}, hist3 = {};

  __syncthreads();

  auto flush4 = [&]() {   // writer lanes only; 12 stores for the last 4 steps
    f16* p0 = outp - 4 * ostep;
    p0[0] = hist0[0]; p0[16] = hist0[1]; p0[32] = hist0[2];
    f16* p1 = outp - 3 * ostep;
    p1[0] = hist1[0]; p1[16] = hist1[1]; p1[32] = hist1[2];
    f16* p2 = outp - 2 * ostep;
    p2[0] = hist2[0]; p2[16] = hist2[1]; p2[32] = hist2[2];
    f16* p3 = outp - 1 * ostep;
    p3[0] = hist3[0]; p3[16] = hist3[1]; p3[32] = hist3[2];
  };

  auto body = [&](int k, const f16x4 g0, const f16x4 g1, const f16x4 g2, const int ph) {
    const f16* hp = hT[k & 1];
    f32x4 acc[3][3];
    {
      const f16x8 af0 = *(const f16x8*)(hp + lq * 8);
#pragma unroll
      for (int s = 0; s < 3; ++s)
#pragma unroll
        for (int q = 0; q < 3; ++q)
          acc[s][q] = __builtin_amdgcn_mfma_f32_16x16x32_f16(af0, wf[s][q][0], bh4[s][q], 0, 0, 0);
    }
#pragma unroll
    for (int kt = 1; kt < 6; ++kt) {
      const f16x8 af = *(const f16x8*)(hp + kt * 32 + lq * 8);
#pragma unroll
      for (int s = 0; s < 3; ++s)
#pragma unroll
        for (int q = 0; q < 3; ++q)
          acc[s][q] = __builtin_amdgcn_mfma_f32_16x16x32_f16(af, wf[s][q][kt], acc[s][q], 0, 0, 0);
    }
    // gates: this lane's 3 cols (dup over lq; acc rows all duplicate -> elem [0])
    f16x4 hcur = {};
    {
      const float ur = (float)g0[0] + acc[0][0][0];
      const float uz = (float)g0[1] + acc[1][0][0];
      const float dr = 1.f + __builtin_amdgcn_exp2f(ur);
      const float dz = 1.f + __builtin_amdgcn_exp2f(uz);
      const float Rp = __builtin_amdgcn_rcpf(dr * dz);
      const float rv = dz * Rp, zv = dr * Rp;
      const float vn = fmaf(rv, acc[2][0][0], (float)g0[2]);
      const float nv = fmaf(-2.f, __builtin_amdgcn_rcpf(1.f + __builtin_amdgcn_exp2f(vn)), 1.f);
      const float hv = nv + zv * (hr0 - nv);
      hr0 = hv; hcur[0] = (f16)hv;
    }
    {
      const float ur = (float)g1[0] + acc[0][1][0];
      const float uz = (float)g1[1] + acc[1][1][0];
      const float dr = 1.f + __builtin_amdgcn_exp2f(ur);
      const float dz = 1.f + __builtin_amdgcn_exp2f(uz);
      const float Rp = __builtin_amdgcn_rcpf(dr * dz);
      const float rv = dz * Rp, zv = dr * Rp;
      const float vn = fmaf(rv, acc[2][1][0], (float)g1[2]);
      const float nv = fmaf(-2.f, __builtin_amdgcn_rcpf(1.f + __builtin_amdgcn_exp2f(vn)), 1.f);
      const float hv = nv + zv * (hr1 - nv);
      hr1 = hv; hcur[1] = (f16)hv;
    }
    {
      const float ur = (float)g2[0] + acc[0][2][0];
      const float uz = (float)g2[1] + acc[1][2][0];
      const float dr = 1.f + __builtin_amdgcn_exp2f(ur);
      const float dz = 1.f + __builtin_amdgcn_exp2f(uz);
      const float Rp = __builtin_amdgcn_rcpf(dr * dz);
      const float rv = dz * Rp, zv = dr * Rp;
      const float vn = fmaf(rv, acc[2][2][0], (float)g2[2]);
      const float nv = fmaf(-2.f, __builtin_amdgcn_rcpf(1.f + __builtin_amdgcn_exp2f(vn)), 1.f);
      const float hv = nv + zv * (hr2 - nv);
      hr2 = hv; hcur[2] = (f16)hv;
    }
    f16* hn = hT[(k & 1) ^ 1];
    if (writer) {
      hn[w * 48 + l16] = hcur[0];
      hn[w * 48 + 16 + l16] = hcur[1];
      hn[w * 48 + 32 + l16] = hcur[2];
      if (last) {
        const int t = fwd ? k : (T_ - 1 - k);
        if (t == T_ - 1) { outp[0] = hcur[0]; outp[16] = hcur[1]; outp[32] = hcur[2]; }
      }
    }
    if (ph == 0) hist0 = hcur;
    else if (ph == 1) hist1 = hcur;
    else if (ph == 2) hist2 = hcur;
    else hist3 = hcur;
    outp += ostep;
    __syncthreads();
  };

  if (nsteps == 1) {
    pr0[0] = *(const f16x4*)(gptr);
    pr1[0] = *(const f16x4*)(gptr + 64);
    pr2[0] = *(const f16x4*)(gptr + 128);
    body(0, pr0[0], pr1[0], pr2[0], 0);
  } else {
    for (int k = 0; k < T_; k += 4) {
      // batched gx loads for this 4-step group (drain amortized at step barriers)
#pragma unroll
      for (int j = 0; j < 4; ++j) {
        const f16* p = gptr + j * gstep;
        pr0[j] = *(const f16x4*)(p);
        pr1[j] = *(const f16x4*)(p + 64);
        pr2[j] = *(const f16x4*)(p + 128);
      }
      gptr += 4 * gstep;
      if (!last && k > 0 && writer) flush4();
      body(k + 0, pr0[0], pr1[0], pr2[0], 0);
      body(k + 1, pr0[1], pr1[1], pr2[1], 1);
      body(k + 2, pr0[2], pr1[2], pr2[2], 2);
      body(k + 3, pr0[3], pr1[3], pr2[3], 3);
    }
    if (!last && writer) flush4();
  }
}

// ---------------- FC head ----------------
__global__ void fc_kernel(const f16* __restrict__ h2, const float* __restrict__ w1,
                          const float* __restrict__ b1, const float* __restrict__ w2,
                          const float* __restrict__ b2, float* __restrict__ y) {
  const int b = blockIdx.x;
  const int i = threadIdx.x;
  __shared__ float hs[384];
  __shared__ float us[128];
  const f16* hp = h2 + ((size_t)(T_ - 1) * B_ + b) * 384;
  for (int k = i; k < 384; k += 128) hs[k] = (float)hp[k];
  __syncthreads();
  float a = b1[i];
  for (int k = 0; k < 384; ++k) a = fmaf(w1[i * 384 + k], hs[k], a);
  us[i] = fmaxf(a, 0.f) * w2[i];
  __syncthreads();
  if (i == 0) {
    float s = b2[0];
    for (int k = 0; k < 128; ++k) s += us[k];
    y[b] = s;
  }
}

extern "C" void kernel_launch(void* const* d_in, const int* in_sizes, int n_in,
                              void* d_out, int out_size, void* d_ws, size_t ws_size,
                              hipStream_t stream) {
  const int* x = (const int*)d_in[0];
  const float* emb = (const float*)d_in[1];
  const float* wih[3] = {(const float*)d_in[2], (const float*)d_in[6], (const float*)d_in[10]};
  const float* whh[3] = {(const float*)d_in[3], (const float*)d_in[7], (const float*)d_in[11]};
  const float* bih[3] = {(const float*)d_in[4], (const float*)d_in[8], (const float*)d_in[12]};
  const float* bhh[3] = {(const float*)d_in[5], (const float*)d_in[9], (const float*)d_in[13]};
  const float* fc1w = (const float*)d_in[14];
  const float* fc1b = (const float*)d_in[15];
  const float* fc2w = (const float*)d_in[16];
  const float* fc2b = (const float*)d_in[17];
  float* y = (float*)d_out;

  char* ws = (char*)d_ws;
  f16* gxb = (f16*)(ws);
  f16* hbuf = (f16*)(ws + OFF_H);
  f16* in0 = hbuf;
  f16* wihf = (f16*)(ws + OFF_WIH);
  f16* whhf = (f16*)(ws + OFF_WHH);

  wconv_kernel<<<1024, 256, 0, stream>>>(wih[0], whh[0], wih[1], whh[1], wih[2], whh[2], wihf, whhf);
  embed_kernel<<<16384, 256, 0, stream>>>(x, emb, in0);

  gx_gemm<128><<<dim3(512, 9), 256, 0, stream>>>(in0, wihf, bih[0], gxb);
  gru_scan<<<256, 256, 0, stream>>>(gxb, whhf, bhh[0], hbuf, 0);
  gx_gemm<384><<<dim3(512, 9), 256, 0, stream>>>(hbuf, wihf + 147456, bih[1], gxb);
  gru_scan<<<256, 256, 0, stream>>>(gxb, whhf + 221184, bhh[1], hbuf, 0);
  gx_gemm<384><<<dim3(512, 9), 256, 0, stream>>>(hbuf, wihf + 147456 + 442368, bih[2], gxb);
  gru_scan<<<256, 256, 0, stream>>>(gxb, whhf + 2 * 221184, bhh[2], hbuf, 1);

  fc_kernel<<<128, 128, 0, stream>>>(hbuf, fc1w, fc1b, fc2w, fc2b, y);
}

// Round 17
// 1426.780 us; speedup vs baseline: 1.3812x; 1.3144x over previous
//
#include <hip/hip_runtime.h>

typedef _Float16 f16;
typedef _Float16 f16x8 __attribute__((ext_vector_type(8)));
typedef _Float16 f16x4 __attribute__((ext_vector_type(4)));
typedef _Float16 f16x2 __attribute__((ext_vector_type(2)));
typedef float f32x4 __attribute__((ext_vector_type(4)));

#define B_ 128
#define T_ 512
#define H_ 192
#define G3 576

// gate prescale constants (folded into weights/biases):
// r,z pre-acts scaled by -log2e  -> sigmoid(u) = rcp(1 + exp2(u~))
// n pre-acts scaled by +2*log2e  -> tanh(v) = 1 - 2*rcp(1 + exp2(v~))
#define SC_RZ (-1.44269504088896f)
#define SC_N  (2.88539008177793f)

// ---- workspace layout (bytes). Total 204,718,080 < 256 MiB. ----
// [0, 150994944)          gxb : gx pre-acts, f16 [d][bblk8(32)][t][w12][lq_s][l16][s][pair]
//                               per (d,bblk8): 512*4608 f16; per t: 4608 f16
// [150994944, 201326592)  hbuf: layer h output, f16 [t][b][384]
//                               (in0 f16 [t][b][128] aliases its first 16.8MB)
// [201326592, 203390976)  wihf: f16 w_ih prescaled (L0 147456, L1 442368, L2 442368)
// [203390976, 204718080)  whhf: f16 w_hh prescaled (3 x 221184)
#define OFF_H   150994944u
#define OFF_WIH 201326592u
#define OFF_WHH 203390976u

__device__ __forceinline__ void gload_lds16(const void* g, void* l) {
  __builtin_amdgcn_global_load_lds(
      (const __attribute__((address_space(1))) unsigned int*)g,
      (__attribute__((address_space(3))) unsigned int*)l, 16, 0, 0);
}

// ---------------- fused prep: embedding gather + weight conversion ----------------
// blocks [0,16384): embed x -> in0 [t][b][128] f16
// blocks [16384,17408): f32->f16 weight conversion with gate prescale
__global__ void prep_kernel(const int* __restrict__ x, const float* __restrict__ emb,
                            f16* __restrict__ o,
                            const float* __restrict__ w0, const float* __restrict__ h0,
                            const float* __restrict__ w1, const float* __restrict__ h1,
                            const float* __restrict__ w2, const float* __restrict__ h2,
                            f16* __restrict__ wih, f16* __restrict__ whh) {
  if (blockIdx.x < 16384) {
    const int row = (blockIdx.x << 2) + (threadIdx.x >> 6);  // b*512+t
    const int lane = threadIdx.x & 63;
    const int b = row >> 9, t = row & 511;
    const int idx = x[row];
    const float2 v = *(const float2*)(emb + ((size_t)idx << 7) + (lane << 1));
    union { f16 h[2]; unsigned u; } p;
    p.h[0] = (f16)v.x;
    p.h[1] = (f16)v.y;
    *(unsigned*)(o + ((size_t)((t << 7) + b) << 7) + (lane << 1)) = p.u;
    return;
  }
  const int bid = blockIdx.x - 16384;
  for (int i = bid * blockDim.x + threadIdx.x; i < 1695744; i += 1024 * 256) {
    if (i < 1032192) {
      int j, din;
      const float* src;
      if (i < 147456) { j = i; din = 128; src = w0; }
      else if (i < 589824) { j = i - 147456; din = 384; src = w1; }
      else { j = i - 589824; din = 384; src = w2; }
      const int row = j / din;            // 0..1151 = [d][576]
      const int sg = (row % 576) / 192;   // gate type r/z/n
      wih[i] = (f16)(src[j] * (sg == 2 ? SC_N : SC_RZ));
    } else {
      int j = i - 1032192, jl;
      const float* src;
      if (j < 221184) { src = h0; jl = j; }
      else if (j < 442368) { src = h1; jl = j - 221184; }
      else { src = h2; jl = j - 442368; }
      const int row = jl / 192;           // 0..1151
      const int sg = (row % 576) / 192;
      whh[j] = (f16)(src[jl] * (sg == 2 ? SC_N : SC_RZ));
    }
  }
}

// ---------------- gx GEMM: gx = X @ w_ih^T + b_ih (f16 MFMA, prescaled) ----------------
// lastmode: layer-2 — bwd gx needed only at t=511. Pure-bwd tile-blocks (nt0>=640)
// early-exit for t!=511; mixed block y=4 masks its bwd stores.
template <int DIN>
__global__ __launch_bounds__(256) void gx_gemm(const f16* __restrict__ A,
                                               const f16* __restrict__ W,
                                               const float* __restrict__ bih,
                                               f16* __restrict__ gxo,
                                               int lastmode) {
  const int t = blockIdx.x;
  const int nt0 = blockIdx.y << 7;
  if (lastmode && nt0 >= 640 && t != 511) return;
  const int tid = threadIdx.x;
  const int lane = tid & 63;
  const int w = tid >> 6;
  const int l16 = lane & 15;
  const int lq = lane >> 4;
  const int wm = (w >> 1) << 6;
  const int wn = (w & 1) << 6;

  __shared__ __align__(16) f16 Al[128 * 128];
  __shared__ __align__(16) f16 Bl[128 * 128];

  f32x4 acc[4][4] = {};

  const int srow = tid >> 4;
  const int sc = tid & 15;

  for (int kk = 0; kk < DIN; kk += 128) {
    __syncthreads();
#pragma unroll
    for (int it = 0; it < 8; ++it) {
      const int r = (it << 4) + srow;
      const int cl = sc ^ (r & 7);
      gload_lds16(A + (size_t)(t * B_ + r) * DIN + kk + cl * 8, Al + (it << 11) + tid * 8);
      const int n = nt0 + r;
      gload_lds16(W + (size_t)n * DIN + kk + cl * 8, Bl + (it << 11) + tid * 8);
    }
    __syncthreads();
#pragma unroll
    for (int kt = 0; kt < 4; ++kt) {
      f16x8 af[4], bf[4];
#pragma unroll
      for (int mt = 0; mt < 4; ++mt) {
        const int r = wm + (mt << 4) + l16;
        const int c = ((kt << 2) + lq) ^ (r & 7);
        af[mt] = *(const f16x8*)(Al + (r << 7) + (c << 3));
      }
#pragma unroll
      for (int nt = 0; nt < 4; ++nt) {
        const int r = wn + (nt << 4) + l16;
        const int c = ((kt << 2) + lq) ^ (r & 7);
        bf[nt] = *(const f16x8*)(Bl + (r << 7) + (c << 3));
      }
#pragma unroll
      for (int mt = 0; mt < 4; ++mt)
#pragma unroll
        for (int nt = 0; nt < 4; ++nt)
          acc[mt][nt] = __builtin_amdgcn_mfma_f32_16x16x32_f16(af[mt], bf[nt], acc[mt][nt], 0, 0, 0);
    }
  }
  // epilogue: + prescaled b_ih; pair layout (verified rounds 8/10/11/12).
  // C frag: row(batch) = lq*4+i, col(gate) = l16.  store slot lq_s = (lq&1) | ((i>>1)<<1).
#pragma unroll
  for (int nt = 0; nt < 4; ++nt) {
    const int ncol = nt0 + wn + (nt << 4);
    const int ntile = ncol >> 4;                 // 0..71
    const int dd = (ntile >= 36) ? 1 : 0;
    if (lastmode && dd == 1 && t != 511) continue;
    const int g = ntile - 36 * dd;
    const int s = g / 12;                        // gate type
    const int c12 = g % 12;                      // scan wave id
    const float bias = bih[ncol + l16] * ((s == 2) ? SC_N : SC_RZ);
#pragma unroll
    for (int mt = 0; mt < 4; ++mt) {
      const int bblk16 = (wm >> 4) + mt;
      const int bblk8 = bblk16 * 2 + (lq >> 1);
      f16x2 p0, p1;
      p0[0] = (f16)(acc[mt][nt][0] + bias);
      p0[1] = (f16)(acc[mt][nt][1] + bias);
      p1[0] = (f16)(acc[mt][nt][2] + bias);
      p1[1] = (f16)(acc[mt][nt][3] + bias);
      const size_t base =
          ((((size_t)(dd * 16 + bblk8) * 512 + t) * 12 + c12) * 4 + (lq & 1)) * 96 +
          l16 * 6 + s * 2;
      *(f16x2*)(gxo + base) = p0;          // rows (lq&1)*4 + {0,1} of the 8-row block
      *(f16x2*)(gxo + base + 192) = p1;    // rows (lq&1)*4 + {2,3}
    }
  }
}

// ---------------- recurrent scan: 8 rows/block, 32 blocks (r12 floor config) ----------------
// 32 blocks x 768 threads (12 waves, 3/SIMD). Block = (bblk8, d), batch rows
// b0..b0+7. Wave w owns gate cols [16w,16w+16) for r,z,n: 18 MFMA/wave/step.
// Duplicate-row A-frags (row=l16&7) spread 8 rows over all 4 lane-quads: 2 gate
// elems/lane, no shuffles. Prescaled gates, merged rcp for r,z.
// Round 17: out-stores batched 4 steps in registers, flushed at the next
// group's top so the per-step __syncthreads vmcnt-drain is store-free 3/4 steps.
__global__ __launch_bounds__(768, 3) void gru_scan(const f16* __restrict__ gx,
                                                   const f16* __restrict__ whh,
                                                   const float* __restrict__ bhh,
                                                   f16* __restrict__ out,
                                                   int last) {
  const int bx = blockIdx.x;
  const int d = bx & 1;
  const int bblk8 = bx >> 1;   // 0..15
  const int b0 = bblk8 << 3;
  const int tid = threadIdx.x;
  const int lane = tid & 63;
  const int w = tid >> 6;      // 0..11
  const int l16 = lane & 15;
  const int lq = lane >> 4;

  // h tile 8x192, XOR-swizzled, double-buffered (3072 B per buffer)
  __shared__ __align__(16) f16 hl[2 * 8 * 192];
  for (int i = tid; i < 2 * 8 * 192; i += 768) hl[i] = (f16)0.f;
  char* cb = (char*)hl;

  int ra[6];
#pragma unroll
  for (int kt = 0; kt < 6; ++kt)
    ra[kt] = (l16 & 7) * 384 + ((kt * 64 + lq * 16) ^ ((l16 & 7) << 4));
  // rows owned by this lane: r0, r0+1  (lq0:{0,1} lq1:{4,5} lq2:{2,3} lq3:{6,7})
  const int r0 = ((lq & 1) << 2) | (lq & 2);
  const int cix = (w * 16 + l16) * 2;
  const int wa0 = r0 * 384 + (cix ^ (r0 << 4));
  const int wa1 = (r0 + 1) * 384 + (cix ^ ((r0 + 1) << 4));
  const bool hi = (lq & 2) != 0;  // use acc elems {2,3} (duplicated rows)

  const f16* whd = whh + (size_t)d * (G3 * H_);
  f16x8 wf[3][6];
#pragma unroll
  for (int s = 0; s < 3; ++s) {
    const int nrow = s * 192 + w * 16 + l16;
#pragma unroll
    for (int kt = 0; kt < 6; ++kt)
      wf[s][kt] = *(const f16x8*)(whd + (size_t)nrow * H_ + kt * 32 + lq * 8);
  }
  f32x4 bh4[3];
#pragma unroll
  for (int s = 0; s < 3; ++s) {
    const float bv = bhh[d * G3 + s * 192 + w * 16 + l16] * ((s == 2) ? SC_N : SC_RZ);
    bh4[s] = (f32x4){bv, bv, bv, bv};
  }

  float hr0 = 0.f, hr1 = 0.f;

  const int nsteps = (last && d == 1) ? 1 : T_;
  const bool fwd = (d == 0);
  const long gstep = fwd ? 4608 : -4608;          // f16 elems per step
  const long ostep = fwd ? (long)B_ * 384 : -(long)B_ * 384;
  const int t0 = fwd ? 0 : (T_ - 1);

  // per-lane gx slot: 6 f16 = [s][pair], 12B
  const f16* gbase = gx + (size_t)(d * 16 + bblk8) * 2359296 +
                     (size_t)(((w * 4 + lq) * 16 + l16) * 6);

  auto ld3 = [](const f16* p, f16x2 (&g)[3]) {
    g[0] = *(const f16x2*)(p);
    g[1] = *(const f16x2*)(p + 2);
    g[2] = *(const f16x2*)(p + 4);
  };

  f16x2 pA[3] = {}, pB[3] = {};
  ld3(gbase + (size_t)t0 * 4608, pA);
  if (nsteps > 1) ld3(gbase + (size_t)t0 * 4608 + gstep, pB);
  const f16* gptr = gbase + (size_t)t0 * 4608 + 2 * gstep;  // 2 steps ahead
  f16* outp = out + ((size_t)t0 * B_ + b0 + r0) * 384 + d * H_ + w * 16 + l16;

  f16x2 hist0 = {}, hist1 = {}, hist2 = {}, hist3 = {};
  __syncthreads();

  auto flush4 = [&]() {  // stores for the previous 4-step group (outp already advanced)
    f16* p0 = outp - 4 * ostep; p0[0] = hist0[0]; p0[384] = hist0[1];
    f16* p1 = outp - 3 * ostep; p1[0] = hist1[0]; p1[384] = hist1[1];
    f16* p2 = outp - 2 * ostep; p2[0] = hist2[0]; p2[384] = hist2[1];
    f16* p3 = outp - 1 * ostep; p3[0] = hist3[0]; p3[384] = hist3[1];
  };

  auto body = [&](int step, int buf, f16x2 (&pc)[3], const int ph) {
    const int bo = buf ? 3072 : 0;
    f32x4 acc[3];
    {
      const f16x8 af0 = *(const f16x8*)(cb + ra[0] + bo);
#pragma unroll
      for (int s = 0; s < 3; ++s)
        acc[s] = __builtin_amdgcn_mfma_f32_16x16x32_f16(af0, wf[s][0], bh4[s], 0, 0, 0);
    }
#pragma unroll
    for (int kt = 1; kt < 6; ++kt) {
      const f16x8 af = *(const f16x8*)(cb + ra[kt] + bo);
#pragma unroll
      for (int s = 0; s < 3; ++s)
        acc[s] = __builtin_amdgcn_mfma_f32_16x16x32_f16(af, wf[s][kt], acc[s], 0, 0, 0);
    }
    // snapshot current gx, issue reload 2 steps ahead
    const f16x2 g0 = pc[0], g1 = pc[1], g2 = pc[2];
    if (step + 2 < nsteps) {
      ld3(gptr, pc);
      gptr += gstep;
    }
    const int bo2 = buf ? 0 : 3072;   // write to other buffer
    // this lane's two gate elements
    const float a0r = hi ? acc[0][2] : acc[0][0];
    const float a0z = hi ? acc[1][2] : acc[1][0];
    const float a0n = hi ? acc[2][2] : acc[2][0];
    const float a1r = hi ? acc[0][3] : acc[0][1];
    const float a1z = hi ? acc[1][3] : acc[1][1];
    const float a1n = hi ? acc[2][3] : acc[2][1];
    f16x2 hcur;
    {
      const float ur = (float)g0[0] + a0r;
      const float uz = (float)g1[0] + a0z;
      const float dr = 1.f + __builtin_amdgcn_exp2f(ur);
      const float dz = 1.f + __builtin_amdgcn_exp2f(uz);
      const float Rp = __builtin_amdgcn_rcpf(dr * dz);
      const float rv = dz * Rp, zv = dr * Rp;
      const float vn = fmaf(rv, a0n, (float)g2[0]);
      const float nv = fmaf(-2.f, __builtin_amdgcn_rcpf(1.f + __builtin_amdgcn_exp2f(vn)), 1.f);
      const float hv = nv + zv * (hr0 - nv);
      hr0 = hv;
      *(f16*)(cb + wa0 + bo2) = (f16)hv;
      hcur[0] = (f16)hv;
    }
    {
      const float ur = (float)g0[1] + a1r;
      const float uz = (float)g1[1] + a1z;
      const float dr = 1.f + __builtin_amdgcn_exp2f(ur);
      const float dz = 1.f + __builtin_amdgcn_exp2f(uz);
      const float Rp = __builtin_amdgcn_rcpf(dr * dz);
      const float rv = dz * Rp, zv = dr * Rp;
      const float vn = fmaf(rv, a1n, (float)g2[1]);
      const float nv = fmaf(-2.f, __builtin_amdgcn_rcpf(1.f + __builtin_amdgcn_exp2f(vn)), 1.f);
      const float hv = nv + zv * (hr1 - nv);
      hr1 = hv;
      *(f16*)(cb + wa1 + bo2) = (f16)hv;
      hcur[1] = (f16)hv;
    }
    if (!last) {
      if (ph == 0) hist0 = hcur;
      else if (ph == 1) hist1 = hcur;
      else if (ph == 2) hist2 = hcur;
      else hist3 = hcur;
    } else {
      const int t = fwd ? step : (T_ - 1 - step);
      if (t == T_ - 1) { outp[0] = hcur[0]; outp[384] = hcur[1]; }
    }
    outp += ostep;
    __syncthreads();
  };

  if (nsteps == 1) {
    body(0, 0, pA, 0);
  } else {
    for (int step = 0; step < T_; step += 4) {
      // flush previous group's out-stores first: they overlap this group's
      // MFMA phase and their drain lands on an already-covered barrier
      if (!last && step > 0) flush4();
      body(step + 0, 0, pA, 0);
      body(step + 1, 1, pB, 1);
      body(step + 2, 0, pA, 2);
      body(step + 3, 1, pB, 3);
    }
    if (!last) flush4();
  }
}

// ---------------- FC head ----------------
__global__ void fc_kernel(const f16* __restrict__ h2, const float* __restrict__ w1,
                          const float* __restrict__ b1, const float* __restrict__ w2,
                          const float* __restrict__ b2, float* __restrict__ y) {
  const int b = blockIdx.x;
  const int i = threadIdx.x;
  __shared__ float hs[384];
  __shared__ float us[128];
  const f16* hp = h2 + ((size_t)(T_ - 1) * B_ + b) * 384;
  for (int k = i; k < 384; k += 128) hs[k] = (float)hp[k];
  __syncthreads();
  float a = b1[i];
  for (int k = 0; k < 384; ++k) a = fmaf(w1[i * 384 + k], hs[k], a);
  us[i] = fmaxf(a, 0.f) * w2[i];
  __syncthreads();
  if (i == 0) {
    float s = b2[0];
    for (int k = 0; k < 128; ++k) s += us[k];
    y[b] = s;
  }
}

extern "C" void kernel_launch(void* const* d_in, const int* in_sizes, int n_in,
                              void* d_out, int out_size, void* d_ws, size_t ws_size,
                              hipStream_t stream) {
  const int* x = (const int*)d_in[0];
  const float* emb = (const float*)d_in[1];
  const float* wih[3] = {(const float*)d_in[2], (const float*)d_in[6], (const float*)d_in[10]};
  const float* whh[3] = {(const float*)d_in[3], (const float*)d_in[7], (const float*)d_in[11]};
  const float* bih[3] = {(const float*)d_in[4], (const float*)d_in[8], (const float*)d_in[12]};
  const float* bhh[3] = {(const float*)d_in[5], (const float*)d_in[9], (const float*)d_in[13]};
  const float* fc1w = (const float*)d_in[14];
  const float* fc1b = (const float*)d_in[15];
  const float* fc2w = (const float*)d_in[16];
  const float* fc2b = (const float*)d_in[17];
  float* y = (float*)d_out;

  char* ws = (char*)d_ws;
  f16* gxb = (f16*)(ws);
  f16* hbuf = (f16*)(ws + OFF_H);
  f16* in0 = hbuf;
  f16* wihf = (f16*)(ws + OFF_WIH);
  f16* whhf = (f16*)(ws + OFF_WHH);

  prep_kernel<<<17408, 256, 0, stream>>>(x, emb, in0, wih[0], whh[0], wih[1], whh[1],
                                         wih[2], whh[2], wihf, whhf);

  gx_gemm<128><<<dim3(512, 9), 256, 0, stream>>>(in0, wihf, bih[0], gxb, 0);
  gru_scan<<<32, 768, 0, stream>>>(gxb, whhf, bhh[0], hbuf, 0);
  gx_gemm<384><<<dim3(512, 9), 256, 0, stream>>>(hbuf, wihf + 147456, bih[1], gxb, 0);
  gru_scan<<<32, 768, 0, stream>>>(gxb, whhf + 221184, bhh[1], hbuf, 0);
  gx_gemm<384><<<dim3(512, 9), 256, 0, stream>>>(hbuf, wihf + 147456 + 442368, bih[2], gxb, 1);
  gru_scan<<<32, 768, 0, stream>>>(gxb, whhf + 2 * 221184, bhh[2], hbuf, 1);

  fc_kernel<<<128, 128, 0, stream>>>(hbuf, fc1w, fc1b, fc2w, fc2b, y);
}